// Round 5
// baseline (9928.204 us; speedup 1.0000x reference)
//
#include <hip/hip_runtime.h>

#define B_    256
#define S_    1024
#define H_    512
#define G4_   2048
#define T_    256
#define NBLK  256
#define NTHR  1024
#define BB    16          // batches per batch-group
#define NBG   16          // batch groups
#define LBN   16          // blocks per batch-group
#define HS2   260         // hi/lo plane row stride in words (256 + 4 pad)
#define AUXC  0x11        // CPol sc0|sc1: coherent read at MALL (agent scope)

typedef short bf8v  __attribute__((ext_vector_type(8)));   // 8 bf16 = 4 VGPR
typedef float f4v   __attribute__((ext_vector_type(4)));
typedef int   i32x4 __attribute__((ext_vector_type(4)));

typedef const __attribute__((address_space(1))) void gas_void;
typedef __attribute__((address_space(3))) void       las_void;

#define PERM_HI 0x07060302u   // [src0.hi16 | src1.hi16]

// Agent-scope (MALL) primitives — the ONLY coherence path used anywhere.
// No sc0-only traffic exists in this kernel: nothing is ever left dirty in
// an XCD L2, so graph replays see exactly what hipMemsetAsync wrote.
__device__ __forceinline__ unsigned ald(const unsigned* a)
{
    return __hip_atomic_load(a, __ATOMIC_RELAXED, __HIP_MEMORY_SCOPE_AGENT);
}
__device__ __forceinline__ void ast(unsigned* a, unsigned v)
{
    __hip_atomic_store(a, v, __ATOMIC_RELAXED, __HIP_MEMORY_SCOPE_AGENT);
}
__device__ __forceinline__ void vm0() { asm volatile("s_waitcnt vmcnt(0)" ::: "memory"); }

// ---------------------------------------------------------------------------
// W2[j][k] = dec_Whh[j][k] + dec_Wih[j]*lin_W[k]; dbias[j] = dec biases fused
// ---------------------------------------------------------------------------
__global__ void fuse_dec_weights(const float* __restrict__ dec_Whh,
                                 const float* __restrict__ dec_Wih,
                                 const float* __restrict__ lin_W,
                                 const float* __restrict__ dec_bih,
                                 const float* __restrict__ dec_bhh,
                                 const float* __restrict__ lin_b,
                                 float* __restrict__ W2,
                                 float* __restrict__ dbias)
{
    int idx = blockIdx.x * 256 + threadIdx.x;
    int j = idx >> 9, k = idx & 511;
    W2[idx] = fmaf(dec_Wih[j], lin_W[k], dec_Whh[idx]);
    if (idx < G4_)
        dbias[idx] = dec_bih[idx] + dec_bhh[idx] + dec_Wih[idx] * lin_b[0];
}

// fast sigmoid/tanh: v_exp + v_rcp (rel err ~1e-7; margin 7x at 6e-5)
__device__ __forceinline__ float fsig(float x)
{
    return __builtin_amdgcn_rcpf(1.0f + __expf(-x));
}
__device__ __forceinline__ float ftanh(float x)
{
    return fmaf(-2.0f, __builtin_amdgcn_rcpf(1.0f + __expf(2.0f * x)), 1.0f);
}

// ---------------------------------------------------------------------------
// Persistent kernel. Baseline compute decomposition (16 waves, gbuf kset
// reduce, split-bf16 3-term MFMA). Sync = per-bg FLAG barrier, agent scope:
//   publish: each leader wave, after storeh + vmcnt(0) drain, lane0 stores
//            ph+1 to its own slot (no RMW, no contention).
//   wait:    wave 0 polls the bg's 64 slots with one coalesced load.
// Invariant (same as validated baseline): a block's slot reaching ph+1
// implies its SY3 passed, hence its stage-reads of the h buffer being
// overwritten next step completed. The drain-then-signal sequence is the
// one hardware-validated in R2 (absmax 6.1e-5).
// ---------------------------------------------------------------------------
__global__ void __launch_bounds__(NTHR)
seq2seq_kernel(const float* __restrict__ inputs,
               const float* __restrict__ enc_Wih,
               const float* __restrict__ enc_bih,
               const float* __restrict__ enc_bhh,
               const float* __restrict__ dec_Wih,
               const float* __restrict__ lin_W,
               const float* __restrict__ lin_b,
               const float* __restrict__ enc_Whh,
               const float* __restrict__ W2,
               const float* __restrict__ dbias,
               unsigned* __restrict__ hiA, unsigned* __restrict__ loA,
               unsigned* __restrict__ hiB, unsigned* __restrict__ loB,
               float* __restrict__ xcor,
               unsigned* __restrict__ bars,
               float* __restrict__ out)
{
    __shared__ unsigned hs_hi[BB * HS2];     // 16.6 KB: h hi-bf16 plane
    __shared__ unsigned hs_lo[BB * HS2];     // 16.6 KB: h lo-bf16 plane
    __shared__ float gbuf[3 * 4 * 2 * 272];  // 26.1 KB: kset partial f4v slots

    const int tid  = threadIdx.x;
    const int w    = tid >> 6;               // wave 0..15
    const int lane = tid & 63;
    const int quad = lane >> 4;              // 0..3
    const int mn   = lane & 15;              // MFMA m/n index
    const int rs   = w & 3;                  // rowset 0..3
    const int ks   = w >> 2;                 // kset 0..3 (128 k each)
    const int bg   = blockIdx.x & (NBG - 1);
    const int lb   = blockIdx.x >> 4;        // hidden-slice owner 0..15
    const int bgbase = bg * BB;
    const bool leader = (ks == 3);
    const int pidx = lb * 16 + rs * 4 + quad;         // hid-pair index
    const int hid0 = lb * 32 + rs * 8 + 2 * quad;

    unsigned* fl     = bars + bg * 64;       // this bg's 64 flag slots
    unsigned* myflag = fl + lb * 4 + rs;     // slot owned by this leader wave

    // A rows: m = mn -> gate = mn&3, hsel = mn>>2; hsub = rs*8 + 2*hsel + p
    i32x4 Ah[2][4], Al[2][4];                // 64 regs: weight frags hi/lo
    auto loadA = [&](const float* __restrict__ Wm) {
        #pragma unroll
        for (int p = 0; p < 2; ++p) {
            const int grow = (mn & 3) * H_ + lb * 32 + rs * 8 + 2 * (mn >> 2) + p;
            const float* rowp = Wm + (size_t)grow * H_ + ks * 128 + quad * 8;
            #pragma unroll
            for (int l = 0; l < 4; ++l) {
                const float* rp = rowp + l * 32;
                float4 f0 = *(const float4*)rp;
                float4 f1 = *(const float4*)(rp + 4);
                unsigned b0 = __float_as_uint(f0.x), b1 = __float_as_uint(f0.y);
                unsigned b2 = __float_as_uint(f0.z), b3 = __float_as_uint(f0.w);
                unsigned b4 = __float_as_uint(f1.x), b5 = __float_as_uint(f1.y);
                unsigned b6 = __float_as_uint(f1.z), b7 = __float_as_uint(f1.w);
                i32x4 hi, lo;
                hi.x = __builtin_amdgcn_perm(b1, b0, PERM_HI);
                hi.y = __builtin_amdgcn_perm(b3, b2, PERM_HI);
                hi.z = __builtin_amdgcn_perm(b5, b4, PERM_HI);
                hi.w = __builtin_amdgcn_perm(b7, b6, PERM_HI);
                float r0 = f0.x - __uint_as_float(b0 & 0xffff0000u);
                float r1 = f0.y - __uint_as_float(b1 & 0xffff0000u);
                float r2 = f0.z - __uint_as_float(b2 & 0xffff0000u);
                float r3 = f0.w - __uint_as_float(b3 & 0xffff0000u);
                float r4 = f1.x - __uint_as_float(b4 & 0xffff0000u);
                float r5 = f1.y - __uint_as_float(b5 & 0xffff0000u);
                float r6 = f1.z - __uint_as_float(b6 & 0xffff0000u);
                float r7 = f1.w - __uint_as_float(b7 & 0xffff0000u);
                lo.x = __builtin_amdgcn_perm(__float_as_uint(r1), __float_as_uint(r0), PERM_HI);
                lo.y = __builtin_amdgcn_perm(__float_as_uint(r3), __float_as_uint(r2), PERM_HI);
                lo.z = __builtin_amdgcn_perm(__float_as_uint(r5), __float_as_uint(r4), PERM_HI);
                lo.w = __builtin_amdgcn_perm(__float_as_uint(r7), __float_as_uint(r6), PERM_HI);
                Ah[p][l] = hi; Al[p][l] = lo;
            }
        }
    };

    // stage: wave w DMAs batch-row (bgbase+w) of both planes into LDS (async)
    auto stage = [&](const unsigned* hi_src, const unsigned* lo_src) {
        const size_t off = (size_t)(bgbase + w) * 256 + lane * 4;
        __builtin_amdgcn_global_load_lds((gas_void*)(hi_src + off),
                                         (las_void*)(hs_hi + w * HS2), 16, 0, AUXC);
        __builtin_amdgcn_global_load_lds((gas_void*)(lo_src + off),
                                         (las_void*)(hs_lo + w * HS2), 16, 0, AUXC);
    };

    // 3-term split-bf16 MFMA over 2 m-tiles x this wave's 128-k range
    auto dots = [&](f4v& acc0, f4v& acc1) {
        acc0 = f4v{0.f, 0.f, 0.f, 0.f};
        acc1 = f4v{0.f, 0.f, 0.f, 0.f};
        #pragma unroll
        for (int l = 0; l < 4; ++l) {
            const int boff = mn * HS2 + ks * 64 + l * 16 + quad * 4;
            i32x4 bhv = *(const i32x4*)(hs_hi + boff);
            i32x4 blv = *(const i32x4*)(hs_lo + boff);
            bf8v bh = __builtin_bit_cast(bf8v, bhv);
            bf8v bl = __builtin_bit_cast(bf8v, blv);
            bf8v a0h = __builtin_bit_cast(bf8v, Ah[0][l]);
            bf8v a0l = __builtin_bit_cast(bf8v, Al[0][l]);
            bf8v a1h = __builtin_bit_cast(bf8v, Ah[1][l]);
            bf8v a1l = __builtin_bit_cast(bf8v, Al[1][l]);
            acc0 = __builtin_amdgcn_mfma_f32_16x16x32_bf16(a0h, bh, acc0, 0, 0, 0);
            acc1 = __builtin_amdgcn_mfma_f32_16x16x32_bf16(a1h, bh, acc1, 0, 0, 0);
            acc0 = __builtin_amdgcn_mfma_f32_16x16x32_bf16(a0l, bh, acc0, 0, 0, 0);
            acc1 = __builtin_amdgcn_mfma_f32_16x16x32_bf16(a1l, bh, acc1, 0, 0, 0);
            acc0 = __builtin_amdgcn_mfma_f32_16x16x32_bf16(a0h, bl, acc0, 0, 0, 0);
            acc1 = __builtin_amdgcn_mfma_f32_16x16x32_bf16(a1h, bl, acc1, 0, 0, 0);
        }
    };

    auto writegb = [&](f4v a0, f4v a1) {     // ks<3 waves park partials
        float* gp = gbuf + ((ks * 4 + rs) * 2) * 272 + quad * 68 + mn * 4;
        *(f4v*)gp = a0;
        *(f4v*)(gp + 272) = a1;
    };
    auto reduceg = [&](f4v& a0, f4v& a1) {   // leader sums 3 parked + own
        const int gb = (rs * 2) * 272 + quad * 68 + mn * 4;
        a0 += *(const f4v*)(gbuf + gb);
        a0 += *(const f4v*)(gbuf + gb + 2176);
        a0 += *(const f4v*)(gbuf + gb + 4352);
        a1 += *(const f4v*)(gbuf + gb + 272);
        a1 += *(const f4v*)(gbuf + gb + 272 + 2176);
        a1 += *(const f4v*)(gbuf + gb + 272 + 4352);
    };

    auto lstm = [&](f4v g, float& cc) -> float {
        float i_ = fsig(g[0]), f_ = fsig(g[1]);
        float g_ = ftanh(g[2]), o_ = fsig(g[3]);
        float cn = fmaf(f_, cc, i_ * g_);
        cc = cn;
        return o_ * ftanh(cn);
    };

    auto storeh = [&](unsigned* hn, unsigned* ln, float h0, float h1) {
        unsigned b0 = __float_as_uint(h0), b1 = __float_as_uint(h1);
        unsigned hiw = __builtin_amdgcn_perm(b1, b0, PERM_HI);
        float r0 = h0 - __uint_as_float(b0 & 0xffff0000u);
        float r1 = h1 - __uint_as_float(b1 & 0xffff0000u);
        unsigned low = __builtin_amdgcn_perm(__float_as_uint(r1),
                                             __float_as_uint(r0), PERM_HI);
        size_t pa = (size_t)(bgbase + mn) * 256 + pidx;
        ast(hn + pa, hiw);
        ast(ln + pa, low);
    };

    // h[b=w]·lin_W from hi/lo planes; result on lane 0 of the wave
    auto proj = [&]() -> float {
        const unsigned* hh = hs_hi + w * HS2 + 4 * lane;
        const unsigned* hl = hs_lo + w * HS2 + 4 * lane;
        uint4 uh = *(const uint4*)hh;
        uint4 ul = *(const uint4*)hl;
        const float4* lwp = (const float4*)(lin_W + 8 * lane);
        float4 v0 = lwp[0], v1 = lwp[1];
        #define RL(h, l) (__uint_as_float((h) << 16) + __uint_as_float((l) << 16))
        #define RH(h, l) (__uint_as_float((h) & 0xffff0000u) + __uint_as_float((l) & 0xffff0000u))
        float s = RL(uh.x, ul.x) * v0.x + RH(uh.x, ul.x) * v0.y;
        s = fmaf(RL(uh.y, ul.y), v0.z, s); s = fmaf(RH(uh.y, ul.y), v0.w, s);
        s = fmaf(RL(uh.z, ul.z), v1.x, s); s = fmaf(RH(uh.z, ul.z), v1.y, s);
        s = fmaf(RL(uh.w, ul.w), v1.z, s); s = fmaf(RH(uh.w, ul.w), v1.w, s);
        #undef RL
        #undef RH
        s += __shfl_down(s, 32); s += __shfl_down(s, 16); s += __shfl_down(s, 8);
        s += __shfl_down(s, 4);  s += __shfl_down(s, 2);  s += __shfl_down(s, 1);
        return s;
    };

    // wait: wave 0, lane i polls slot i (one coalesced load per iteration)
    unsigned wd = 0;                         // cumulative watchdog
    auto wait_ph = [&](unsigned tgt) {
        const unsigned* fp = fl + lane;
        for (;;) {
            unsigned v = ald(fp);
            if (__all((int)(v >= tgt))) break;
            if (++wd > (1u << 26)) break;    // deadlock -> fast wrong answer
            __builtin_amdgcn_s_sleep(1);
        }
    };

    const float linb = lin_b[0];

    // encoder per-cell constants (leaders only)
    float encW[2][4], encB[2][4];
    if (leader) {
        #pragma unroll
        for (int p = 0; p < 2; ++p)
            #pragma unroll
            for (int g4 = 0; g4 < 4; ++g4) {
                const int j = g4 * H_ + hid0 + p;
                encW[p][g4] = enc_Wih[j];
                encB[p][g4] = enc_bih[j] + enc_bhh[j];
            }
    }

    loadA(enc_Whh);

    // h_0 = 0; each leader wave drains its own stores then publishes 1
    if (leader) {
        size_t pa = (size_t)(bgbase + mn) * 256 + pidx;
        ast(hiA + pa, 0u);
        ast(loA + pa, 0u);
        vm0();
        if (lane == 0) ast(myflag, 1u);
    }

    float cc0 = 0.f, cc1 = 0.f;
    unsigned *hic = hiA, *loc = loA, *hin = hiB, *lon = loB;
    unsigned ph = 1;

    // ---------------- encoder: 1024 steps ----------------
    #pragma unroll 1
    for (int t = 0; t < S_; ++t) {
        if (w == 0) wait_ph(ph);
        __syncthreads();                  // SYA: release on flags
        stage(hic, loc);
        float xv = leader ? inputs[(size_t)(bgbase + mn) * S_ + t] : 0.f;
        __syncthreads();                  // SY2: DMA landed
        f4v acc0, acc1;
        dots(acc0, acc1);
        if (!leader) writegb(acc0, acc1);
        __syncthreads();                  // SY3: partials parked, hs reads done
        if (leader) {
            reduceg(acc0, acc1);
            #pragma unroll
            for (int g4 = 0; g4 < 4; ++g4) {
                acc0[g4] += fmaf(xv, encW[0][g4], encB[0][g4]);
                acc1[g4] += fmaf(xv, encW[1][g4], encB[1][g4]);
            }
            float h0 = lstm(acc0, cc0);
            float h1 = lstm(acc1, cc1);
            storeh(hin, lon, h0, h1);
            vm0();                         // h at MALL before the signal
            if (lane == 0) ast(myflag, ph + 1);
        }
        ++ph;
        unsigned* t1 = hic; hic = hin; hin = t1;
        unsigned* t2 = loc; loc = lon; lon = t2;
    }

    // ---------------- xcor phase + decoder weight swap ----------------
    if (w == 0) wait_ph(ph);
    __syncthreads();                      // SYA
    if (lb == 0) stage(hic, loc);
    loadA(W2);
    if (lb == 0) {
        __syncthreads();                  // SY2 (lb is block-uniform)
        float s = proj();
        if (lane == 0) {
            float x0 = inputs[(size_t)(bgbase + w) * S_ + (S_ - 1)];
            ast((unsigned*)&xcor[bgbase + w], __float_as_uint(x0 - (s + linb)));
        }
    }
    __syncthreads();                      // SY3: xcor stores drained per-wave
    if (leader) {
        vm0();
        if (lane == 0) ast(myflag, ph + 1);
    }
    ++ph;

    // ---------------- decoder: 256 steps ----------------
    #pragma unroll 1
    for (int t = 0; t < T_; ++t) {
        if (w == 0) wait_ph(ph);
        __syncthreads();                  // SYA
        stage(hic, loc);
        f4v db0, db1;
        if (leader) {                     // fused decoder biases (L1-hot)
            #pragma unroll
            for (int g4 = 0; g4 < 4; ++g4) {
                float2 d = *(const float2*)(dbias + g4 * H_ + hid0);
                db0[g4] = d.x; db1[g4] = d.y;
            }
        }
        __syncthreads();                  // SY2
        f4v acc0, acc1;
        dots(acc0, acc1);
        if (!leader) writegb(acc0, acc1);
        __syncthreads();                  // SY3
        if (lb == 0 && t > 0) {           // out[:, t-1] = h_t·lin_W + lin_b
            float s = proj();
            if (lane == 0)
                out[(size_t)(bgbase + w) * T_ + (t - 1)] = s + linb;
        }
        if (leader) {
            reduceg(acc0, acc1);
            acc0 += db0;
            acc1 += db1;
            if (t == 0) {                 // true x0 correction through dec_Wih
                float xc = __uint_as_float(
                    ald((const unsigned*)&xcor[bgbase + mn]));
                #pragma unroll
                for (int g4 = 0; g4 < 4; ++g4) {
                    float2 dw = *(const float2*)(dec_Wih + g4 * H_ + hid0);
                    acc0[g4] = fmaf(xc, dw.x, acc0[g4]);
                    acc1[g4] = fmaf(xc, dw.y, acc1[g4]);
                }
            }
            float h0 = lstm(acc0, cc0);
            float h1 = lstm(acc1, cc1);
            storeh(hin, lon, h0, h1);
            vm0();
            if (lane == 0) ast(myflag, ph + 1);
        }
        ++ph;
        unsigned* t1 = hic; hic = hin; hin = t1;
        unsigned* t2 = loc; loc = lon; lon = t2;
    }

    // ---------------- epilogue: out[:, T-1] ----------------
    if (w == 0) wait_ph(ph);
    __syncthreads();
    if (lb == 0) {
        stage(hic, loc);
        __syncthreads();
        float s = proj();
        if (lane == 0)
            out[(size_t)(bgbase + w) * T_ + (T_ - 1)] = s + linb;
    }
}

// ---------------------------------------------------------------------------
extern "C" void kernel_launch(void* const* d_in, const int* in_sizes, int n_in,
                              void* d_out, int out_size, void* d_ws, size_t ws_size,
                              hipStream_t stream)
{
    (void)in_sizes; (void)n_in; (void)out_size; (void)ws_size;

    const float* inputs  = (const float*)d_in[0];
    const float* enc_Wih = (const float*)d_in[1];
    const float* enc_Whh = (const float*)d_in[2];
    const float* enc_bih = (const float*)d_in[3];
    const float* enc_bhh = (const float*)d_in[4];
    const float* dec_Wih = (const float*)d_in[5];
    const float* dec_Whh = (const float*)d_in[6];
    const float* dec_bih = (const float*)d_in[7];
    const float* dec_bhh = (const float*)d_in[8];
    const float* lin_W   = (const float*)d_in[9];
    const float* lin_b   = (const float*)d_in[10];
    float* out = (float*)d_out;

    // ws: W2 (4MB) | dbias (8KB) | hiA|loA|hiB|loB (1MB) | xcor | flags (4KB)
    float* W2      = (float*)d_ws;
    float* dbias   = W2 + (size_t)G4_ * H_;
    unsigned* hiA  = (unsigned*)(dbias + G4_);
    unsigned* loA  = hiA + (size_t)B_ * 256;
    unsigned* hiB  = loA + (size_t)B_ * 256;
    unsigned* loB  = hiB + (size_t)B_ * 256;
    float* xcor    = (float*)(loB + (size_t)B_ * 256);
    unsigned* bars = (unsigned*)(xcor + B_);

    hipMemsetAsync((void*)bars, 0, NBG * 64 * sizeof(unsigned), stream);

    hipLaunchKernelGGL(fuse_dec_weights, dim3((G4_ * H_) / 256), dim3(256), 0, stream,
                       dec_Whh, dec_Wih, lin_W, dec_bih, dec_bhh, lin_b, W2, dbias);

    void* args[] = {
        (void*)&inputs, (void*)&enc_Wih, (void*)&enc_bih, (void*)&enc_bhh,
        (void*)&dec_Wih, (void*)&lin_W, (void*)&lin_b,
        (void*)&enc_Whh, (void*)&W2, (void*)&dbias,
        (void*)&hiA, (void*)&loA, (void*)&hiB, (void*)&loB,
        (void*)&xcor, (void*)&bars, (void*)&out
    };
    hipLaunchCooperativeKernel((void*)seq2seq_kernel, dim3(NBLK), dim3(NTHR),
                               args, 0, stream);
}

// Round 6
// 6117.826 us; speedup vs baseline: 1.6228x; 1.6228x over previous
//
#include <hip/hip_runtime.h>

#define B_    256
#define S_    1024
#define H_    512
#define G4_   2048
#define T_    256
#define NBLK  256
#define NTHR  1024
#define BB    16          // batches per batch-group
#define NBG   16          // batch groups
#define LBN   16          // blocks per batch-group
#define HS2   260         // hi/lo plane row stride in words (256 + 4 pad)
#define AUXC  0x11        // CPol sc0|sc1: coherent read at MALL (agent scope)

typedef short bf8v  __attribute__((ext_vector_type(8)));   // 8 bf16 = 4 VGPR
typedef float f4v   __attribute__((ext_vector_type(4)));
typedef int   i32x4 __attribute__((ext_vector_type(4)));

typedef const __attribute__((address_space(1))) void gas_void;
typedef __attribute__((address_space(3))) void       las_void;

#define PERM_HI 0x07060302u   // [src0.hi16 | src1.hi16]

// Agent-scope (MALL) primitives — the only cross-block coherence path.
__device__ __forceinline__ unsigned ald(const unsigned* a)
{
    return __hip_atomic_load(a, __ATOMIC_RELAXED, __HIP_MEMORY_SCOPE_AGENT);
}
__device__ __forceinline__ void ast(unsigned* a, unsigned v)
{
    __hip_atomic_store(a, v, __ATOMIC_RELAXED, __HIP_MEMORY_SCOPE_AGENT);
}
__device__ __forceinline__ void aadd(unsigned* a)
{
    __hip_atomic_fetch_add(a, 1u, __ATOMIC_RELAXED, __HIP_MEMORY_SCOPE_AGENT);
}
__device__ __forceinline__ void vm0() { asm volatile("s_waitcnt vmcnt(0)" ::: "memory"); }

// ---------------------------------------------------------------------------
// W2[j][k] = dec_Whh[j][k] + dec_Wih[j]*lin_W[k]; dbias[j] = dec biases fused
// ---------------------------------------------------------------------------
__global__ void fuse_dec_weights(const float* __restrict__ dec_Whh,
                                 const float* __restrict__ dec_Wih,
                                 const float* __restrict__ lin_W,
                                 const float* __restrict__ dec_bih,
                                 const float* __restrict__ dec_bhh,
                                 const float* __restrict__ lin_b,
                                 float* __restrict__ W2,
                                 float* __restrict__ dbias)
{
    int idx = blockIdx.x * 256 + threadIdx.x;
    int j = idx >> 9, k = idx & 511;
    W2[idx] = fmaf(dec_Wih[j], lin_W[k], dec_Whh[idx]);
    if (idx < G4_)
        dbias[idx] = dec_bih[idx] + dec_bhh[idx] + dec_Wih[idx] * lin_b[0];
}

// fast sigmoid/tanh: v_exp + v_rcp (rel err ~1e-7; margin 7x at 6e-5)
__device__ __forceinline__ float fsig(float x)
{
    return __builtin_amdgcn_rcpf(1.0f + __expf(-x));
}
__device__ __forceinline__ float ftanh(float x)
{
    return fmaf(-2.0f, __builtin_amdgcn_rcpf(1.0f + __expf(2.0f * x)), 1.0f);
}

// ---------------------------------------------------------------------------
// Persistent kernel. Baseline compute decomposition (validated, 3706us) with
// the SAME barrier protocol shape (16 RMWs -> one MALL line per bg; scalar
// pollers; s_sleep), restructured for latency:
//   publish: leaders drain own h-stores (vm0) then ds_add an LDS counter;
//            w15 waits for 4 LDS ticks, then issues the block's single
//            MALL fetch_add.  (Posting ~300-500cy earlier than the baseline's
//            post-__syncthreads add; removes one __syncthreads per step.)
//   entry:   w0 lane0 polls the counter (spin-then-sleep), then SYA releases.
// Invariant unchanged: a block's add implies all its waves passed SY3, hence
// all its stage-reads of the buffer being overwritten next step completed.
// ---------------------------------------------------------------------------
__global__ void __launch_bounds__(NTHR)
seq2seq_kernel(const float* __restrict__ inputs,
               const float* __restrict__ enc_Wih,
               const float* __restrict__ enc_bih,
               const float* __restrict__ enc_bhh,
               const float* __restrict__ dec_Wih,
               const float* __restrict__ lin_W,
               const float* __restrict__ lin_b,
               const float* __restrict__ enc_Whh,
               const float* __restrict__ W2,
               const float* __restrict__ dbias,
               unsigned* __restrict__ hiA, unsigned* __restrict__ loA,
               unsigned* __restrict__ hiB, unsigned* __restrict__ loB,
               float* __restrict__ xcor,
               unsigned* __restrict__ bars,
               float* __restrict__ out)
{
    __shared__ unsigned hs_hi[BB * HS2];     // 16.6 KB: h hi-bf16 plane
    __shared__ unsigned hs_lo[BB * HS2];     // 16.6 KB: h lo-bf16 plane
    __shared__ float gbuf[3 * 4 * 2 * 272];  // 26.1 KB: kset partial f4v slots
    __shared__ unsigned lcnt;                // leader mini-barrier (monotonic)

    const int tid  = threadIdx.x;
    const int w    = tid >> 6;               // wave 0..15
    const int lane = tid & 63;
    const int quad = lane >> 4;              // 0..3
    const int mn   = lane & 15;              // MFMA m/n index
    const int rs   = w & 3;                  // rowset 0..3
    const int ks   = w >> 2;                 // kset 0..3 (128 k each)
    const int bg   = blockIdx.x & (NBG - 1);
    const int lb   = blockIdx.x >> 4;        // hidden-slice owner 0..15
    const int bgbase = bg * BB;
    const bool leader = (ks == 3);
    const int pidx = lb * 16 + rs * 4 + quad;         // hid-pair index
    const int hid0 = lb * 32 + rs * 8 + 2 * quad;

    unsigned* arr = bars + bg * 64;          // per-bg monotonic counter

    if (tid == 0) lcnt = 0u;

    // A rows: m = mn -> gate = mn&3, hsel = mn>>2; hsub = rs*8 + 2*hsel + p
    i32x4 Ah[2][4], Al[2][4];                // 64 regs: weight frags hi/lo
    auto loadA = [&](const float* __restrict__ Wm) {
        #pragma unroll
        for (int p = 0; p < 2; ++p) {
            const int grow = (mn & 3) * H_ + lb * 32 + rs * 8 + 2 * (mn >> 2) + p;
            const float* rowp = Wm + (size_t)grow * H_ + ks * 128 + quad * 8;
            #pragma unroll
            for (int l = 0; l < 4; ++l) {
                const float* rp = rowp + l * 32;
                float4 f0 = *(const float4*)rp;
                float4 f1 = *(const float4*)(rp + 4);
                unsigned b0 = __float_as_uint(f0.x), b1 = __float_as_uint(f0.y);
                unsigned b2 = __float_as_uint(f0.z), b3 = __float_as_uint(f0.w);
                unsigned b4 = __float_as_uint(f1.x), b5 = __float_as_uint(f1.y);
                unsigned b6 = __float_as_uint(f1.z), b7 = __float_as_uint(f1.w);
                i32x4 hi, lo;
                hi.x = __builtin_amdgcn_perm(b1, b0, PERM_HI);
                hi.y = __builtin_amdgcn_perm(b3, b2, PERM_HI);
                hi.z = __builtin_amdgcn_perm(b5, b4, PERM_HI);
                hi.w = __builtin_amdgcn_perm(b7, b6, PERM_HI);
                float r0 = f0.x - __uint_as_float(b0 & 0xffff0000u);
                float r1 = f0.y - __uint_as_float(b1 & 0xffff0000u);
                float r2 = f0.z - __uint_as_float(b2 & 0xffff0000u);
                float r3 = f0.w - __uint_as_float(b3 & 0xffff0000u);
                float r4 = f1.x - __uint_as_float(b4 & 0xffff0000u);
                float r5 = f1.y - __uint_as_float(b5 & 0xffff0000u);
                float r6 = f1.z - __uint_as_float(b6 & 0xffff0000u);
                float r7 = f1.w - __uint_as_float(b7 & 0xffff0000u);
                lo.x = __builtin_amdgcn_perm(__float_as_uint(r1), __float_as_uint(r0), PERM_HI);
                lo.y = __builtin_amdgcn_perm(__float_as_uint(r3), __float_as_uint(r2), PERM_HI);
                lo.z = __builtin_amdgcn_perm(__float_as_uint(r5), __float_as_uint(r4), PERM_HI);
                lo.w = __builtin_amdgcn_perm(__float_as_uint(r7), __float_as_uint(r6), PERM_HI);
                Ah[p][l] = hi; Al[p][l] = lo;
            }
        }
    };

    // stage: wave w DMAs batch-row (bgbase+w) of both planes into LDS (async)
    auto stage = [&](const unsigned* hi_src, const unsigned* lo_src) {
        const size_t off = (size_t)(bgbase + w) * 256 + lane * 4;
        __builtin_amdgcn_global_load_lds((gas_void*)(hi_src + off),
                                         (las_void*)(hs_hi + w * HS2), 16, 0, AUXC);
        __builtin_amdgcn_global_load_lds((gas_void*)(lo_src + off),
                                         (las_void*)(hs_lo + w * HS2), 16, 0, AUXC);
    };

    // 3-term split-bf16 MFMA over 2 m-tiles x this wave's 128-k range
    auto dots = [&](f4v& acc0, f4v& acc1) {
        acc0 = f4v{0.f, 0.f, 0.f, 0.f};
        acc1 = f4v{0.f, 0.f, 0.f, 0.f};
        #pragma unroll
        for (int l = 0; l < 4; ++l) {
            const int boff = mn * HS2 + ks * 64 + l * 16 + quad * 4;
            i32x4 bhv = *(const i32x4*)(hs_hi + boff);
            i32x4 blv = *(const i32x4*)(hs_lo + boff);
            bf8v bh = __builtin_bit_cast(bf8v, bhv);
            bf8v bl = __builtin_bit_cast(bf8v, blv);
            bf8v a0h = __builtin_bit_cast(bf8v, Ah[0][l]);
            bf8v a0l = __builtin_bit_cast(bf8v, Al[0][l]);
            bf8v a1h = __builtin_bit_cast(bf8v, Ah[1][l]);
            bf8v a1l = __builtin_bit_cast(bf8v, Al[1][l]);
            acc0 = __builtin_amdgcn_mfma_f32_16x16x32_bf16(a0h, bh, acc0, 0, 0, 0);
            acc1 = __builtin_amdgcn_mfma_f32_16x16x32_bf16(a1h, bh, acc1, 0, 0, 0);
            acc0 = __builtin_amdgcn_mfma_f32_16x16x32_bf16(a0l, bh, acc0, 0, 0, 0);
            acc1 = __builtin_amdgcn_mfma_f32_16x16x32_bf16(a1l, bh, acc1, 0, 0, 0);
            acc0 = __builtin_amdgcn_mfma_f32_16x16x32_bf16(a0h, bl, acc0, 0, 0, 0);
            acc1 = __builtin_amdgcn_mfma_f32_16x16x32_bf16(a1h, bl, acc1, 0, 0, 0);
        }
    };

    auto writegb = [&](f4v a0, f4v a1) {     // ks<3 waves park partials
        float* gp = gbuf + ((ks * 4 + rs) * 2) * 272 + quad * 68 + mn * 4;
        *(f4v*)gp = a0;
        *(f4v*)(gp + 272) = a1;
    };
    auto reduceg = [&](f4v& a0, f4v& a1) {   // leader sums 3 parked + own
        const int gb = (rs * 2) * 272 + quad * 68 + mn * 4;
        a0 += *(const f4v*)(gbuf + gb);
        a0 += *(const f4v*)(gbuf + gb + 2176);
        a0 += *(const f4v*)(gbuf + gb + 4352);
        a1 += *(const f4v*)(gbuf + gb + 272);
        a1 += *(const f4v*)(gbuf + gb + 272 + 2176);
        a1 += *(const f4v*)(gbuf + gb + 272 + 4352);
    };

    auto lstm = [&](f4v g, float& cc) -> float {
        float i_ = fsig(g[0]), f_ = fsig(g[1]);
        float g_ = ftanh(g[2]), o_ = fsig(g[3]);
        float cn = fmaf(f_, cc, i_ * g_);
        cc = cn;
        return o_ * ftanh(cn);
    };

    auto storeh = [&](unsigned* hn, unsigned* ln, float h0, float h1) {
        unsigned b0 = __float_as_uint(h0), b1 = __float_as_uint(h1);
        unsigned hiw = __builtin_amdgcn_perm(b1, b0, PERM_HI);
        float r0 = h0 - __uint_as_float(b0 & 0xffff0000u);
        float r1 = h1 - __uint_as_float(b1 & 0xffff0000u);
        unsigned low = __builtin_amdgcn_perm(__float_as_uint(r1),
                                             __float_as_uint(r0), PERM_HI);
        size_t pa = (size_t)(bgbase + mn) * 256 + pidx;
        ast(hn + pa, hiw);
        ast(ln + pa, low);
    };

    // h[b=w]·lin_W from hi/lo planes; result on lane 0 of the wave
    auto proj = [&]() -> float {
        const unsigned* hh = hs_hi + w * HS2 + 4 * lane;
        const unsigned* hl = hs_lo + w * HS2 + 4 * lane;
        uint4 uh = *(const uint4*)hh;
        uint4 ul = *(const uint4*)hl;
        const float4* lwp = (const float4*)(lin_W + 8 * lane);
        float4 v0 = lwp[0], v1 = lwp[1];
        #define RL(h, l) (__uint_as_float((h) << 16) + __uint_as_float((l) << 16))
        #define RH(h, l) (__uint_as_float((h) & 0xffff0000u) + __uint_as_float((l) & 0xffff0000u))
        float s = RL(uh.x, ul.x) * v0.x + RH(uh.x, ul.x) * v0.y;
        s = fmaf(RL(uh.y, ul.y), v0.z, s); s = fmaf(RH(uh.y, ul.y), v0.w, s);
        s = fmaf(RL(uh.z, ul.z), v1.x, s); s = fmaf(RH(uh.z, ul.z), v1.y, s);
        s = fmaf(RL(uh.w, ul.w), v1.z, s); s = fmaf(RH(uh.w, ul.w), v1.w, s);
        #undef RL
        #undef RH
        s += __shfl_down(s, 32); s += __shfl_down(s, 16); s += __shfl_down(s, 8);
        s += __shfl_down(s, 4);  s += __shfl_down(s, 2);  s += __shfl_down(s, 1);
        return s;
    };

    // publish helper: leader waves tick LDS; w15 issues the single MALL add
    auto ldstick = [&]() {
        __hip_atomic_fetch_add(&lcnt, 1u, __ATOMIC_RELAXED,
                               __HIP_MEMORY_SCOPE_WORKGROUP);
    };
    unsigned wdl = 0;
    auto w15_add = [&](unsigned lt) {        // called by w15 lane0 only
        while (__hip_atomic_load(&lcnt, __ATOMIC_RELAXED,
                                 __HIP_MEMORY_SCOPE_WORKGROUP) < lt) {
            if (++wdl > (1u << 26)) break;
        }
        aadd(arr);
    };

    // entry wait: one scalar poller, spin-then-sleep
    unsigned wd = 0;
    auto entry_wait = [&](unsigned tgt) {    // called by w0 lane0 only
        int sp = 0;
        while (ald(arr) < tgt) {
            if (++sp > 6) __builtin_amdgcn_s_sleep(1);
            if (++wd > (1u << 26)) break;
        }
    };

    const float linb = lin_b[0];

    // encoder per-cell constants (leaders only)
    float encW[2][4], encB[2][4];
    if (leader) {
        #pragma unroll
        for (int p = 0; p < 2; ++p)
            #pragma unroll
            for (int g4 = 0; g4 < 4; ++g4) {
                const int j = g4 * H_ + hid0 + p;
                encW[p][g4] = enc_Wih[j];
                encB[p][g4] = enc_bih[j] + enc_bhh[j];
            }
    }

    loadA(enc_Whh);
    __syncthreads();                         // lcnt init visible

    // h_0 = 0; leaders drain, tick; w15 posts the block's add
    if (leader) {
        size_t pa = (size_t)(bgbase + mn) * 256 + pidx;
        ast(hiA + pa, 0u);
        ast(loA + pa, 0u);
        vm0();
        if (lane == 0) ldstick();
    }
    if (w == 15 && lane == 0) w15_add(4u);

    float cc0 = 0.f, cc1 = 0.f;
    unsigned *hic = hiA, *loc = loA, *hin = hiB, *lon = loB;
    unsigned atgt = 16u;                     // arr target for current entry
    unsigned ltgt = 4u;                      // lcnt value reached at init

    // ---------------- encoder: 1024 steps ----------------
    #pragma unroll 1
    for (int t = 0; t < S_; ++t) {
        ltgt += 4u;
        float xv = leader ? inputs[(size_t)(bgbase + mn) * S_ + t] : 0.f;
        if (w == 0 && lane == 0) entry_wait(atgt);
        __syncthreads();                  // SYA: release on counter
        stage(hic, loc);
        __syncthreads();                  // SY2: DMA landed
        f4v acc0, acc1;
        dots(acc0, acc1);
        if (!leader) writegb(acc0, acc1);
        __syncthreads();                  // SY3: partials parked, hs reads done
        if (leader) {
            reduceg(acc0, acc1);
            #pragma unroll
            for (int g4 = 0; g4 < 4; ++g4) {
                acc0[g4] += fmaf(xv, encW[0][g4], encB[0][g4]);
                acc1[g4] += fmaf(xv, encW[1][g4], encB[1][g4]);
            }
            float h0 = lstm(acc0, cc0);
            float h1 = lstm(acc1, cc1);
            storeh(hin, lon, h0, h1);
            vm0();                         // own h at MALL
            if (lane == 0) ldstick();
        }
        if (w == 15 && lane == 0) w15_add(ltgt);
        atgt += 16u;
        unsigned* t1 = hic; hic = hin; hin = t1;
        unsigned* t2 = loc; loc = lon; lon = t2;
    }

    // ---------------- xcor phase + decoder weight swap ----------------
    if (w == 0 && lane == 0) entry_wait(atgt);
    __syncthreads();                      // SYA
    if (lb == 0) {                        // xcor[b] = x0_true - (h·lin_W + b)
        stage(hic, loc);
        __syncthreads();
        float s = proj();
        if (lane == 0) {
            float x0 = inputs[(size_t)(bgbase + w) * S_ + (S_ - 1)];
            ast((unsigned*)&xcor[bgbase + w], __float_as_uint(x0 - (s + linb)));
        }
    }
    loadA(W2);
    __syncthreads();                      // drains xcor stores (per-wave vmcnt0)
    if (w == 15 && lane == 0) aadd(arr);  // no ltgt bump (no leader ticks)
    atgt += 16u;

    // hoisted decoder constants (leaders only)
    f4v db0{0.f,0.f,0.f,0.f}, db1{0.f,0.f,0.f,0.f};
    if (leader) {
        #pragma unroll
        for (int g4 = 0; g4 < 4; ++g4) {
            float2 d = *(const float2*)(dbias + g4 * H_ + hid0);
            db0[g4] = d.x; db1[g4] = d.y;
        }
    }

    // ---------------- decoder: 256 steps ----------------
    #pragma unroll 1
    for (int t = 0; t < T_; ++t) {
        ltgt += 4u;
        if (w == 0 && lane == 0) entry_wait(atgt);
        __syncthreads();                  // SYA
        stage(hic, loc);
        __syncthreads();                  // SY2
        f4v acc0, acc1;
        dots(acc0, acc1);
        if (!leader) writegb(acc0, acc1);
        __syncthreads();                  // SY3
        if (leader) {                     // publish FIRST (critical path)
            reduceg(acc0, acc1);
            acc0 += db0;
            acc1 += db1;
            if (t == 0) {                 // true x0 correction through dec_Wih
                float xc = __uint_as_float(
                    ald((const unsigned*)&xcor[bgbase + mn]));
                #pragma unroll
                for (int g4 = 0; g4 < 4; ++g4) {
                    float2 dw = *(const float2*)(dec_Wih + g4 * H_ + hid0);
                    acc0[g4] = fmaf(xc, dw.x, acc0[g4]);
                    acc1[g4] = fmaf(xc, dw.y, acc1[g4]);
                }
            }
            float h0 = lstm(acc0, cc0);
            float h1 = lstm(acc1, cc1);
            storeh(hin, lon, h0, h1);
            vm0();
            if (lane == 0) ldstick();
        }
        if (w == 15 && lane == 0) w15_add(ltgt);
        if (lb == 0 && t > 0) {           // out[:, t-1] = h_t·lin_W + lin_b
            float s = proj();             // after publish: off critical path
            if (lane == 0)
                out[(size_t)(bgbase + w) * T_ + (t - 1)] = s + linb;
        }
        atgt += 16u;
        unsigned* t1 = hic; hic = hin; hin = t1;
        unsigned* t2 = loc; loc = lon; lon = t2;
    }

    // ---------------- epilogue: out[:, T-1] ----------------
    if (w == 0 && lane == 0) entry_wait(atgt);
    __syncthreads();
    if (lb == 0) {
        stage(hic, loc);
        __syncthreads();
        float s = proj();
        if (lane == 0)
            out[(size_t)(bgbase + w) * T_ + (T_ - 1)] = s + linb;
    }
}

// ---------------------------------------------------------------------------
extern "C" void kernel_launch(void* const* d_in, const int* in_sizes, int n_in,
                              void* d_out, int out_size, void* d_ws, size_t ws_size,
                              hipStream_t stream)
{
    (void)in_sizes; (void)n_in; (void)out_size; (void)ws_size;

    const float* inputs  = (const float*)d_in[0];
    const float* enc_Wih = (const float*)d_in[1];
    const float* enc_Whh = (const float*)d_in[2];
    const float* enc_bih = (const float*)d_in[3];
    const float* enc_bhh = (const float*)d_in[4];
    const float* dec_Wih = (const float*)d_in[5];
    const float* dec_Whh = (const float*)d_in[6];
    const float* dec_bih = (const float*)d_in[7];
    const float* dec_bhh = (const float*)d_in[8];
    const float* lin_W   = (const float*)d_in[9];
    const float* lin_b   = (const float*)d_in[10];
    float* out = (float*)d_out;

    // ws: W2 (4MB) | dbias (8KB) | hiA|loA|hiB|loB (1MB) | xcor | bars
    float* W2      = (float*)d_ws;
    float* dbias   = W2 + (size_t)G4_ * H_;
    unsigned* hiA  = (unsigned*)(dbias + G4_);
    unsigned* loA  = hiA + (size_t)B_ * 256;
    unsigned* hiB  = loA + (size_t)B_ * 256;
    unsigned* loB  = hiB + (size_t)B_ * 256;
    float* xcor    = (float*)(loB + (size_t)B_ * 256);
    unsigned* bars = (unsigned*)(xcor + B_);

    hipMemsetAsync((void*)bars, 0, NBG * 64 * sizeof(unsigned), stream);

    hipLaunchKernelGGL(fuse_dec_weights, dim3((G4_ * H_) / 256), dim3(256), 0, stream,
                       dec_Whh, dec_Wih, lin_W, dec_bih, dec_bhh, lin_b, W2, dbias);

    void* args[] = {
        (void*)&inputs, (void*)&enc_Wih, (void*)&enc_bih, (void*)&enc_bhh,
        (void*)&dec_Wih, (void*)&lin_W, (void*)&lin_b,
        (void*)&enc_Whh, (void*)&W2, (void*)&dbias,
        (void*)&hiA, (void*)&loA, (void*)&hiB, (void*)&loB,
        (void*)&xcor, (void*)&bars, (void*)&out
    };
    hipLaunchCooperativeKernel((void*)seq2seq_kernel, dim3(NBLK), dim3(NTHR),
                               args, 0, stream);
}

// Round 7
// 4474.585 us; speedup vs baseline: 2.2188x; 1.3672x over previous
//
#include <hip/hip_runtime.h>

#define B_    256
#define S_    1024
#define H_    512
#define G4_   2048
#define T_    256
#define NBLK  256
#define NTHR  1024
#define BB    16          // batches per batch-group
#define NBG   16          // batch groups
#define LBN   16          // blocks per batch-group
#define HS2   261         // LDS h-plane row stride in words (256 + 5 pad):
                          // dots bank = (5*mn+4*quad)%32 -> max 3-way (was 8-way at 260)
#define GQS   69          // gbuf quad stride in floats: bank = (4*mn+5*q)%32 -> exact 2-way
#define AUXC  0x11        // CPol sc0|sc1: coherent read at MALL (agent scope)

typedef short bf8v  __attribute__((ext_vector_type(8)));   // 8 bf16 = 4 VGPR
typedef float f4v   __attribute__((ext_vector_type(4)));
typedef int   i32x4 __attribute__((ext_vector_type(4)));

typedef const __attribute__((address_space(1))) void gas_void;
typedef __attribute__((address_space(3))) void       las_void;

#define PERM_HI 0x07060302u   // [src0.hi16 | src1.hi16] (low short = src1.hi16)

// ---------------------------------------------------------------------------
// W2[j][k] = dec_Whh[j][k] + dec_Wih[j]*lin_W[k]; dbias[j] = dec biases fused
// ---------------------------------------------------------------------------
__global__ void fuse_dec_weights(const float* __restrict__ dec_Whh,
                                 const float* __restrict__ dec_Wih,
                                 const float* __restrict__ lin_W,
                                 const float* __restrict__ dec_bih,
                                 const float* __restrict__ dec_bhh,
                                 const float* __restrict__ lin_b,
                                 float* __restrict__ W2,
                                 float* __restrict__ dbias)
{
    int idx = blockIdx.x * 256 + threadIdx.x;
    int j = idx >> 9, k = idx & 511;
    W2[idx] = fmaf(dec_Wih[j], lin_W[k], dec_Whh[idx]);
    if (idx < G4_)
        dbias[idx] = dec_bih[idx] + dec_bhh[idx] + dec_Wih[idx] * lin_b[0];
}

// fast sigmoid/tanh: v_exp + v_rcp (rel err ~1e-7; margin 7x at 6e-5)
__device__ __forceinline__ float fsig(float x)
{
    return __builtin_amdgcn_rcpf(1.0f + __expf(-x));
}
__device__ __forceinline__ float ftanh(float x)
{
    return fmaf(-2.0f, __builtin_amdgcn_rcpf(1.0f + __expf(2.0f * x)), 1.0f);
}

// ---------------------------------------------------------------------------
// Per-bg barrier: ONE monotonic agent-scope counter (sc1/MALL), no fences.
// Validated protocol (3706us): last arriver skips polling entirely.
// ---------------------------------------------------------------------------
__device__ __forceinline__ void bg_barrier(unsigned* arr, int ph)
{
    __syncthreads();
    if (threadIdx.x == 0) {
        unsigned prev = __hip_atomic_fetch_add(arr, 1u, __ATOMIC_RELAXED,
                                               __HIP_MEMORY_SCOPE_AGENT);
        const unsigned target = (unsigned)(ph + 1) * LBN;
        if (prev != target - 1u) {
            while (__hip_atomic_load(arr, __ATOMIC_RELAXED,
                                     __HIP_MEMORY_SCOPE_AGENT) < target)
                __builtin_amdgcn_s_sleep(1);
        }
    }
    __syncthreads();
}

// ---------------------------------------------------------------------------
// Persistent kernel — EXACT validated baseline structure (3706us). Changes
// this round are LDS-layout only (bank-conflict fixes) + decoder bias hoist:
//   HS2 260->261, gbuf quad stride 68->69.  Sync protocol untouched.
// ---------------------------------------------------------------------------
__global__ void __launch_bounds__(NTHR)
seq2seq_kernel(const float* __restrict__ inputs,
               const float* __restrict__ enc_Wih,
               const float* __restrict__ enc_bih,
               const float* __restrict__ enc_bhh,
               const float* __restrict__ dec_Wih,
               const float* __restrict__ lin_W,
               const float* __restrict__ lin_b,
               const float* __restrict__ enc_Whh,
               const float* __restrict__ W2,
               const float* __restrict__ dbias,
               unsigned* __restrict__ hiA, unsigned* __restrict__ loA,
               unsigned* __restrict__ hiB, unsigned* __restrict__ loB,
               float* __restrict__ xcor,
               unsigned* __restrict__ bars,
               float* __restrict__ out)
{
    __shared__ unsigned hs_hi[BB * HS2];     // 16.7 KB: h hi-bf16 plane
    __shared__ unsigned hs_lo[BB * HS2];     // 16.7 KB: h lo-bf16 plane
    __shared__ float gbuf[3 * 4 * 2 * 272];  // 26.1 KB: kset partial f4v slots

    const int tid  = threadIdx.x;
    const int w    = tid >> 6;               // wave 0..15
    const int lane = tid & 63;
    const int quad = lane >> 4;              // 0..3
    const int mn   = lane & 15;              // MFMA m/n index
    const int rs   = w & 3;                  // rowset 0..3
    const int ks   = w >> 2;                 // kset 0..3 (128 k each)
    const int bg   = blockIdx.x & (NBG - 1);
    const int lb   = blockIdx.x >> 4;        // hidden-slice owner 0..15
    const int bgbase = bg * BB;
    const bool leader = (ks == 3);

    unsigned* arr = bars + bg * 64;

    // A rows: m = mn -> gate = mn&3, hsel = mn>>2; hsub = rs*8 + 2*hsel + p
    i32x4 Ah[2][4], Al[2][4];                // 64 regs: weight frags hi/lo
    auto loadA = [&](const float* __restrict__ W) {
        #pragma unroll
        for (int p = 0; p < 2; ++p) {
            const int grow = (mn & 3) * H_ + lb * 32 + rs * 8 + 2 * (mn >> 2) + p;
            const float* rowp = W + (size_t)grow * H_ + ks * 128 + quad * 8;
            #pragma unroll
            for (int l = 0; l < 4; ++l) {
                const float* rp = rowp + l * 32;
                float4 f0 = *(const float4*)rp;
                float4 f1 = *(const float4*)(rp + 4);
                unsigned b0 = __float_as_uint(f0.x), b1 = __float_as_uint(f0.y);
                unsigned b2 = __float_as_uint(f0.z), b3 = __float_as_uint(f0.w);
                unsigned b4 = __float_as_uint(f1.x), b5 = __float_as_uint(f1.y);
                unsigned b6 = __float_as_uint(f1.z), b7 = __float_as_uint(f1.w);
                i32x4 hi, lo;
                hi.x = __builtin_amdgcn_perm(b1, b0, PERM_HI);
                hi.y = __builtin_amdgcn_perm(b3, b2, PERM_HI);
                hi.z = __builtin_amdgcn_perm(b5, b4, PERM_HI);
                hi.w = __builtin_amdgcn_perm(b7, b6, PERM_HI);
                float r0 = f0.x - __uint_as_float(b0 & 0xffff0000u);
                float r1 = f0.y - __uint_as_float(b1 & 0xffff0000u);
                float r2 = f0.z - __uint_as_float(b2 & 0xffff0000u);
                float r3 = f0.w - __uint_as_float(b3 & 0xffff0000u);
                float r4 = f1.x - __uint_as_float(b4 & 0xffff0000u);
                float r5 = f1.y - __uint_as_float(b5 & 0xffff0000u);
                float r6 = f1.z - __uint_as_float(b6 & 0xffff0000u);
                float r7 = f1.w - __uint_as_float(b7 & 0xffff0000u);
                lo.x = __builtin_amdgcn_perm(__float_as_uint(r1), __float_as_uint(r0), PERM_HI);
                lo.y = __builtin_amdgcn_perm(__float_as_uint(r3), __float_as_uint(r2), PERM_HI);
                lo.z = __builtin_amdgcn_perm(__float_as_uint(r5), __float_as_uint(r4), PERM_HI);
                lo.w = __builtin_amdgcn_perm(__float_as_uint(r7), __float_as_uint(r6), PERM_HI);
                Ah[p][l] = hi; Al[p][l] = lo;
            }
        }
    };

    // stage: wave w DMAs batch-row (bgbase+w) of both planes into LDS (async)
    auto stage = [&](const unsigned* hi_src, const unsigned* lo_src) {
        const size_t off = (size_t)(bgbase + w) * 256 + lane * 4;
        __builtin_amdgcn_global_load_lds((gas_void*)(hi_src + off),
                                         (las_void*)(hs_hi + w * HS2), 16, 0, AUXC);
        __builtin_amdgcn_global_load_lds((gas_void*)(lo_src + off),
                                         (las_void*)(hs_lo + w * HS2), 16, 0, AUXC);
    };

    // 3-term split-bf16 MFMA over 2 m-tiles x this wave's 128-k range
    auto dots = [&](f4v& acc0, f4v& acc1) {
        acc0 = f4v{0.f, 0.f, 0.f, 0.f};
        acc1 = f4v{0.f, 0.f, 0.f, 0.f};
        #pragma unroll
        for (int l = 0; l < 4; ++l) {
            const int boff = mn * HS2 + ks * 64 + l * 16 + quad * 4;
            i32x4 bhv = *(const i32x4*)(hs_hi + boff);
            i32x4 blv = *(const i32x4*)(hs_lo + boff);
            bf8v bh = __builtin_bit_cast(bf8v, bhv);
            bf8v bl = __builtin_bit_cast(bf8v, blv);
            bf8v a0h = __builtin_bit_cast(bf8v, Ah[0][l]);
            bf8v a0l = __builtin_bit_cast(bf8v, Al[0][l]);
            bf8v a1h = __builtin_bit_cast(bf8v, Ah[1][l]);
            bf8v a1l = __builtin_bit_cast(bf8v, Al[1][l]);
            acc0 = __builtin_amdgcn_mfma_f32_16x16x32_bf16(a0h, bh, acc0, 0, 0, 0);
            acc1 = __builtin_amdgcn_mfma_f32_16x16x32_bf16(a1h, bh, acc1, 0, 0, 0);
            acc0 = __builtin_amdgcn_mfma_f32_16x16x32_bf16(a0l, bh, acc0, 0, 0, 0);
            acc1 = __builtin_amdgcn_mfma_f32_16x16x32_bf16(a1l, bh, acc1, 0, 0, 0);
            acc0 = __builtin_amdgcn_mfma_f32_16x16x32_bf16(a0h, bl, acc0, 0, 0, 0);
            acc1 = __builtin_amdgcn_mfma_f32_16x16x32_bf16(a1h, bl, acc1, 0, 0, 0);
        }
    };

    auto writegb = [&](f4v a0, f4v a1) {     // ks<3 waves park partials
        float* gp = gbuf + ((ks * 4 + rs) * 2) * 272 + quad * GQS + mn * 4;
        *(f4v*)gp = a0;
        *(f4v*)(gp + 272) = a1;
    };
    auto reduceg = [&](f4v& a0, f4v& a1) {   // leader sums 3 parked + own
        const int gb = (rs * 2) * 272 + quad * GQS + mn * 4;
        a0 += *(const f4v*)(gbuf + gb);
        a0 += *(const f4v*)(gbuf + gb + 2176);
        a0 += *(const f4v*)(gbuf + gb + 4352);
        a1 += *(const f4v*)(gbuf + gb + 272);
        a1 += *(const f4v*)(gbuf + gb + 272 + 2176);
        a1 += *(const f4v*)(gbuf + gb + 272 + 4352);
    };

    // LSTM cell on an accumulator holding (i,f,g,o)
    auto lstm = [&](f4v g, float& cc) -> float {
        float i_ = fsig(g[0]), f_ = fsig(g[1]);
        float g_ = ftanh(g[2]), o_ = fsig(g[3]);
        float cn = fmaf(f_, cc, i_ * g_);
        cc = cn;
        return o_ * ftanh(cn);
    };

    // leader thread owns adjacent hid pair (hid0, hid0+1), batch mn
    const int pidx = lb * 16 + rs * 4 + quad;         // hid-pair index
    const int hid0 = lb * 32 + rs * 8 + 2 * quad;

    auto storeh = [&](unsigned* hn, unsigned* ln, float h0, float h1) {
        unsigned b0 = __float_as_uint(h0), b1 = __float_as_uint(h1);
        unsigned hiw = __builtin_amdgcn_perm(b1, b0, PERM_HI);
        float r0 = h0 - __uint_as_float(b0 & 0xffff0000u);
        float r1 = h1 - __uint_as_float(b1 & 0xffff0000u);
        unsigned low = __builtin_amdgcn_perm(__float_as_uint(r1),
                                             __float_as_uint(r0), PERM_HI);
        size_t pa = (size_t)(bgbase + mn) * 256 + pidx;
        __hip_atomic_store(hn + pa, hiw, __ATOMIC_RELAXED, __HIP_MEMORY_SCOPE_AGENT);
        __hip_atomic_store(ln + pa, low, __ATOMIC_RELAXED, __HIP_MEMORY_SCOPE_AGENT);
    };

    // h[b=w]·lin_W from hi/lo planes; result on lane 0 of the wave
    auto proj = [&]() -> float {
        const unsigned* hh = hs_hi + w * HS2 + 4 * lane;
        const unsigned* hl = hs_lo + w * HS2 + 4 * lane;
        uint4 uh = *(const uint4*)hh;
        uint4 ul = *(const uint4*)hl;
        const float4* lwp = (const float4*)(lin_W + 8 * lane);
        float4 v0 = lwp[0], v1 = lwp[1];
        #define RL(h, l) (__uint_as_float((h) << 16) + __uint_as_float((l) << 16))
        #define RH(h, l) (__uint_as_float((h) & 0xffff0000u) + __uint_as_float((l) & 0xffff0000u))
        float s = RL(uh.x, ul.x) * v0.x + RH(uh.x, ul.x) * v0.y;
        s = fmaf(RL(uh.y, ul.y), v0.z, s); s = fmaf(RH(uh.y, ul.y), v0.w, s);
        s = fmaf(RL(uh.z, ul.z), v1.x, s); s = fmaf(RH(uh.z, ul.z), v1.y, s);
        s = fmaf(RL(uh.w, ul.w), v1.z, s); s = fmaf(RH(uh.w, ul.w), v1.w, s);
        #undef RL
        #undef RH
        s += __shfl_down(s, 32); s += __shfl_down(s, 16); s += __shfl_down(s, 8);
        s += __shfl_down(s, 4);  s += __shfl_down(s, 2);  s += __shfl_down(s, 1);
        return s;
    };

    const float linb = lin_b[0];

    // encoder per-cell constants (leaders only; 16 regs)
    float encW[2][4], encB[2][4];
    if (leader) {
        #pragma unroll
        for (int p = 0; p < 2; ++p)
            #pragma unroll
            for (int g4 = 0; g4 < 4; ++g4) {
                const int j = g4 * H_ + hid0 + p;
                encW[p][g4] = enc_Wih[j];
                encB[p][g4] = enc_bih[j] + enc_bhh[j];
            }
    }

    loadA(enc_Whh);

    // h_0 = 0 (leaders cover all 512 cells per block)
    if (leader) {
        size_t pa = (size_t)(bgbase + mn) * 256 + pidx;
        __hip_atomic_store(hiA + pa, 0u, __ATOMIC_RELAXED, __HIP_MEMORY_SCOPE_AGENT);
        __hip_atomic_store(loA + pa, 0u, __ATOMIC_RELAXED, __HIP_MEMORY_SCOPE_AGENT);
    }

    float cc0 = 0.f, cc1 = 0.f;
    unsigned *hic = hiA, *loc = loA, *hin = hiB, *lon = loB;
    int ph = 0;

    // ---------------- encoder: 1024 steps ----------------
    #pragma unroll 1
    for (int t = 0; t < S_; ++t) {
        bg_barrier(arr, ph++);
        stage(hic, loc);
        float xv = leader ? inputs[(size_t)(bgbase + mn) * S_ + t] : 0.f;
        __syncthreads();
        f4v acc0, acc1;
        dots(acc0, acc1);
        if (!leader) writegb(acc0, acc1);
        __syncthreads();
        if (leader) {
            reduceg(acc0, acc1);
            #pragma unroll
            for (int g4 = 0; g4 < 4; ++g4) {
                acc0[g4] += fmaf(xv, encW[0][g4], encB[0][g4]);
                acc1[g4] += fmaf(xv, encW[1][g4], encB[1][g4]);
            }
            float h0 = lstm(acc0, cc0);
            float h1 = lstm(acc1, cc1);
            storeh(hin, lon, h0, h1);
        }
        unsigned* t1 = hic; hic = hin; hin = t1;
        unsigned* t2 = loc; loc = lon; lon = t2;
    }

    // ---------------- xcor phase + decoder weight swap ----------------
    bg_barrier(arr, ph++);
    if (lb == 0) {          // xcor[b] = x0_true - (h_enc·lin_W + lin_b)
        stage(hic, loc);
        __syncthreads();
        float s = proj();
        if (lane == 0) {
            float x0 = inputs[(size_t)(bgbase + w) * S_ + (S_ - 1)];
            __hip_atomic_store(&xcor[bgbase + w],
                               __float_as_uint(0) * 0.f + (x0 - (s + linb)),
                               __ATOMIC_RELAXED, __HIP_MEMORY_SCOPE_AGENT);
        }
    }
    loadA(W2);

    // hoisted loop-invariant decoder biases (leaders only)
    f4v db0{0.f,0.f,0.f,0.f}, db1{0.f,0.f,0.f,0.f};
    if (leader) {
        #pragma unroll
        for (int g4 = 0; g4 < 4; ++g4) {
            float2 d = *(const float2*)(dbias + g4 * H_ + hid0);
            db0[g4] = d.x; db1[g4] = d.y;
        }
    }

    // ---------------- decoder: 256 steps ----------------
    #pragma unroll 1
    for (int t = 0; t < T_; ++t) {
        bg_barrier(arr, ph++);
        stage(hic, loc);
        __syncthreads();
        f4v acc0, acc1;
        dots(acc0, acc1);
        if (!leader) writegb(acc0, acc1);
        __syncthreads();
        if (lb == 0 && t > 0) {        // out[:, t-1] = h_t·lin_W + lin_b
            float s = proj();
            if (lane == 0)
                out[(size_t)(bgbase + w) * T_ + (t - 1)] = s + linb;
        }
        if (leader) {
            reduceg(acc0, acc1);
            acc0 += db0;
            acc1 += db1;
            if (t == 0) {   // true x0 correction through dec_Wih
                float xc = __hip_atomic_load(&xcor[bgbase + mn],
                                             __ATOMIC_RELAXED, __HIP_MEMORY_SCOPE_AGENT);
                #pragma unroll
                for (int g4 = 0; g4 < 4; ++g4) {
                    float2 dw = *(const float2*)(dec_Wih + g4 * H_ + hid0);
                    acc0[g4] = fmaf(xc, dw.x, acc0[g4]);
                    acc1[g4] = fmaf(xc, dw.y, acc1[g4]);
                }
            }
            float h0 = lstm(acc0, cc0);
            float h1 = lstm(acc1, cc1);
            storeh(hin, lon, h0, h1);
        }
        unsigned* t1 = hic; hic = hin; hin = t1;
        unsigned* t2 = loc; loc = lon; lon = t2;
    }

    // ---------------- epilogue: out[:, T-1] ----------------
    bg_barrier(arr, ph++);
    if (lb == 0) {
        stage(hic, loc);
        __syncthreads();
        float s = proj();
        if (lane == 0)
            out[(size_t)(bgbase + w) * T_ + (T_ - 1)] = s + linb;
    }
}

// ---------------------------------------------------------------------------
extern "C" void kernel_launch(void* const* d_in, const int* in_sizes, int n_in,
                              void* d_out, int out_size, void* d_ws, size_t ws_size,
                              hipStream_t stream)
{
    (void)in_sizes; (void)n_in; (void)out_size; (void)ws_size;

    const float* inputs  = (const float*)d_in[0];
    const float* enc_Wih = (const float*)d_in[1];
    const float* enc_Whh = (const float*)d_in[2];
    const float* enc_bih = (const float*)d_in[3];
    const float* enc_bhh = (const float*)d_in[4];
    const float* dec_Wih = (const float*)d_in[5];
    const float* dec_Whh = (const float*)d_in[6];
    const float* dec_bih = (const float*)d_in[7];
    const float* dec_bhh = (const float*)d_in[8];
    const float* lin_W   = (const float*)d_in[9];
    const float* lin_b   = (const float*)d_in[10];
    float* out = (float*)d_out;

    // ws: W2 (4MB) | dbias (8KB) | hiA|loA|hiB|loB (1MB) | xcor | bars
    float* W2      = (float*)d_ws;
    float* dbias   = W2 + (size_t)G4_ * H_;
    unsigned* hiA  = (unsigned*)(dbias + G4_);
    unsigned* loA  = hiA + (size_t)B_ * 256;
    unsigned* hiB  = loA + (size_t)B_ * 256;
    unsigned* loB  = hiB + (size_t)B_ * 256;
    float* xcor    = (float*)(loB + (size_t)B_ * 256);
    unsigned* bars = (unsigned*)(xcor + B_);

    hipMemsetAsync((void*)bars, 0, NBG * 64 * sizeof(unsigned), stream);

    hipLaunchKernelGGL(fuse_dec_weights, dim3((G4_ * H_) / 256), dim3(256), 0, stream,
                       dec_Whh, dec_Wih, lin_W, dec_bih, dec_bhh, lin_b, W2, dbias);

    void* args[] = {
        (void*)&inputs, (void*)&enc_Wih, (void*)&enc_bih, (void*)&enc_bhh,
        (void*)&dec_Wih, (void*)&lin_W, (void*)&lin_b,
        (void*)&enc_Whh, (void*)&W2, (void*)&dbias,
        (void*)&hiA, (void*)&loA, (void*)&hiB, (void*)&loB,
        (void*)&xcor, (void*)&bars, (void*)&out
    };
    hipLaunchCooperativeKernel((void*)seq2seq_kernel, dim3(NBLK), dim3(NTHR),
                               args, 0, stream);
}

// Round 9
// 3605.253 us; speedup vs baseline: 2.7538x; 1.2411x over previous
//
#include <hip/hip_runtime.h>

#define B_    256
#define S_    1024
#define H_    512
#define G4_   2048
#define T_    256
#define NBLK  256
#define NTHR  1024
#define BB    16          // batches per batch-group
#define NBG   16          // batch groups
#define LBN   16          // blocks per batch-group
#define HS2   260         // hi/lo plane row stride in words (256 + 4 pad)
#define AUXC  0x11        // CPol sc0|sc1: coherent read at MALL (agent scope)

typedef short bf8v  __attribute__((ext_vector_type(8)));   // 8 bf16 = 4 VGPR
typedef float f4v   __attribute__((ext_vector_type(4)));
typedef int   i32x4 __attribute__((ext_vector_type(4)));

typedef const __attribute__((address_space(1))) void gas_void;
typedef __attribute__((address_space(3))) void       las_void;

#define PERM_HI 0x07060302u   // [src0.hi16 | src1.hi16] (low short = src1.hi16)

// ---------------------------------------------------------------------------
// W2[j][k] = dec_Whh[j][k] + dec_Wih[j]*lin_W[k]; dbias[j] = dec biases fused
// ---------------------------------------------------------------------------
__global__ void fuse_dec_weights(const float* __restrict__ dec_Whh,
                                 const float* __restrict__ dec_Wih,
                                 const float* __restrict__ lin_W,
                                 const float* __restrict__ dec_bih,
                                 const float* __restrict__ dec_bhh,
                                 const float* __restrict__ lin_b,
                                 float* __restrict__ W2,
                                 float* __restrict__ dbias)
{
    int idx = blockIdx.x * 256 + threadIdx.x;
    int j = idx >> 9, k = idx & 511;
    W2[idx] = fmaf(dec_Wih[j], lin_W[k], dec_Whh[idx]);
    if (idx < G4_)
        dbias[idx] = dec_bih[idx] + dec_bhh[idx] + dec_Wih[idx] * lin_b[0];
}

// fast sigmoid/tanh: v_exp + v_rcp (rel err ~1e-7; margin 7x at 6e-5)
__device__ __forceinline__ float fsig(float x)
{
    return __builtin_amdgcn_rcpf(1.0f + __expf(-x));
}
__device__ __forceinline__ float ftanh(float x)
{
    return fmaf(-2.0f, __builtin_amdgcn_rcpf(1.0f + __expf(2.0f * x)), 1.0f);
}

// ---------------------------------------------------------------------------
// Per-bg barrier: ONE monotonic agent-scope counter (sc1/MALL), no fences.
// Validated R3/R5/R6/R8 of the original session (absmax 6e-5).
// Protocol notes (hard-won this session — do not restructure):
//  * 16 RMWs -> one line, scalar pollers, s_sleep: every variant tried
//    (64 RMWs, store-flag wide-poll, LDS-pre-aggregated early post)
//    regressed 20-170%.  Last-arriver-skips-poll keeps the straggler off
//    the poll path; store drain rides the __syncthreads vmcnt wait.
// ---------------------------------------------------------------------------
__device__ __forceinline__ void bg_barrier(unsigned* arr, int ph)
{
    __syncthreads();
    if (threadIdx.x == 0) {
        unsigned prev = __hip_atomic_fetch_add(arr, 1u, __ATOMIC_RELAXED,
                                               __HIP_MEMORY_SCOPE_AGENT);
        const unsigned target = (unsigned)(ph + 1) * LBN;
        if (prev != target - 1u) {
            while (__hip_atomic_load(arr, __ATOMIC_RELAXED,
                                     __HIP_MEMORY_SCOPE_AGENT) < target)
                __builtin_amdgcn_s_sleep(1);
        }
    }
    __syncthreads();
}

// ---------------------------------------------------------------------------
// Persistent kernel. h lives in global as TWO pre-split planes (hi/lo bf16
// pairs packed in u32). stage() = 2 global_load_lds per wave (async, sc0|sc1).
// MFMA row map m = hsel*4 + gate, hsub = rs*8 + 2*quad + p: the C-fragment
// thread holds all 4 gates of one (hid,batch) cell in acc[0..3] — LSTM
// nonlinearity runs directly on accumulators. Only the 4-kset reduction
// goes through LDS (b128 writes by ks<3, b128 reads by ks==3 leaders).
// LDS layout note (R7): HS2 must stay 260 / gbuf quad stride 68 — the
// 16B alignment of b128 accesses dominates; +1-style padding splits them
// and DOUBLES SQ_LDS_BANK_CONFLICT (1.99e8 -> 3.99e8, +20% time).
// ---------------------------------------------------------------------------
__global__ void __launch_bounds__(NTHR)
seq2seq_kernel(const float* __restrict__ inputs,
               const float* __restrict__ enc_Wih,
               const float* __restrict__ enc_bih,
               const float* __restrict__ enc_bhh,
               const float* __restrict__ dec_Wih,
               const float* __restrict__ lin_W,
               const float* __restrict__ lin_b,
               const float* __restrict__ enc_Whh,
               const float* __restrict__ W2,
               const float* __restrict__ dbias,
               unsigned* __restrict__ hiA, unsigned* __restrict__ loA,
               unsigned* __restrict__ hiB, unsigned* __restrict__ loB,
               float* __restrict__ xcor,
               unsigned* __restrict__ bars,
               float* __restrict__ out)
{
    __shared__ unsigned hs_hi[BB * HS2];     // 16.6 KB: h hi-bf16 plane
    __shared__ unsigned hs_lo[BB * HS2];     // 16.6 KB: h lo-bf16 plane
    __shared__ float gbuf[3 * 4 * 2 * 272];  // 26.1 KB: kset partial f4v slots

    const int tid  = threadIdx.x;
    const int w    = tid >> 6;               // wave 0..15
    const int lane = tid & 63;
    const int quad = lane >> 4;              // 0..3
    const int mn   = lane & 15;              // MFMA m/n index
    const int rs   = w & 3;                  // rowset 0..3
    const int ks   = w >> 2;                 // kset 0..3 (128 k each)
    const int bg   = blockIdx.x & (NBG - 1);
    const int lb   = blockIdx.x >> 4;        // hidden-slice owner 0..15
    const int bgbase = bg * BB;
    const bool leader = (ks == 3);

    unsigned* arr = bars + bg * 64;

    // A rows: m = mn -> gate = mn&3, hsel = mn>>2; hsub = rs*8 + 2*hsel + p
    i32x4 Ah[2][4], Al[2][4];                // 64 regs: weight frags hi/lo
    auto loadA = [&](const float* __restrict__ W) {
        #pragma unroll
        for (int p = 0; p < 2; ++p) {
            const int grow = (mn & 3) * H_ + lb * 32 + rs * 8 + 2 * (mn >> 2) + p;
            const float* rowp = W + (size_t)grow * H_ + ks * 128 + quad * 8;
            #pragma unroll
            for (int l = 0; l < 4; ++l) {
                const float* rp = rowp + l * 32;
                float4 f0 = *(const float4*)rp;
                float4 f1 = *(const float4*)(rp + 4);
                unsigned b0 = __float_as_uint(f0.x), b1 = __float_as_uint(f0.y);
                unsigned b2 = __float_as_uint(f0.z), b3 = __float_as_uint(f0.w);
                unsigned b4 = __float_as_uint(f1.x), b5 = __float_as_uint(f1.y);
                unsigned b6 = __float_as_uint(f1.z), b7 = __float_as_uint(f1.w);
                i32x4 hi, lo;
                hi.x = __builtin_amdgcn_perm(b1, b0, PERM_HI);
                hi.y = __builtin_amdgcn_perm(b3, b2, PERM_HI);
                hi.z = __builtin_amdgcn_perm(b5, b4, PERM_HI);
                hi.w = __builtin_amdgcn_perm(b7, b6, PERM_HI);
                float r0 = f0.x - __uint_as_float(b0 & 0xffff0000u);
                float r1 = f0.y - __uint_as_float(b1 & 0xffff0000u);
                float r2 = f0.z - __uint_as_float(b2 & 0xffff0000u);
                float r3 = f0.w - __uint_as_float(b3 & 0xffff0000u);
                float r4 = f1.x - __uint_as_float(b4 & 0xffff0000u);
                float r5 = f1.y - __uint_as_float(b5 & 0xffff0000u);
                float r6 = f1.z - __uint_as_float(b6 & 0xffff0000u);
                float r7 = f1.w - __uint_as_float(b7 & 0xffff0000u);
                lo.x = __builtin_amdgcn_perm(__float_as_uint(r1), __float_as_uint(r0), PERM_HI);
                lo.y = __builtin_amdgcn_perm(__float_as_uint(r3), __float_as_uint(r2), PERM_HI);
                lo.z = __builtin_amdgcn_perm(__float_as_uint(r5), __float_as_uint(r4), PERM_HI);
                lo.w = __builtin_amdgcn_perm(__float_as_uint(r7), __float_as_uint(r6), PERM_HI);
                Ah[p][l] = hi; Al[p][l] = lo;
            }
        }
    };

    // stage: wave w DMAs batch-row (bgbase+w) of both planes into LDS (async)
    auto stage = [&](const unsigned* hi_src, const unsigned* lo_src) {
        const size_t off = (size_t)(bgbase + w) * 256 + lane * 4;
        __builtin_amdgcn_global_load_lds((gas_void*)(hi_src + off),
                                         (las_void*)(hs_hi + w * HS2), 16, 0, AUXC);
        __builtin_amdgcn_global_load_lds((gas_void*)(lo_src + off),
                                         (las_void*)(hs_lo + w * HS2), 16, 0, AUXC);
    };

    // 3-term split-bf16 MFMA over 2 m-tiles x this wave's 128-k range
    auto dots = [&](f4v& acc0, f4v& acc1) {
        acc0 = f4v{0.f, 0.f, 0.f, 0.f};
        acc1 = f4v{0.f, 0.f, 0.f, 0.f};
        #pragma unroll
        for (int l = 0; l < 4; ++l) {
            const int boff = mn * HS2 + ks * 64 + l * 16 + quad * 4;
            i32x4 bhv = *(const i32x4*)(hs_hi + boff);
            i32x4 blv = *(const i32x4*)(hs_lo + boff);
            bf8v bh = __builtin_bit_cast(bf8v, bhv);
            bf8v bl = __builtin_bit_cast(bf8v, blv);
            bf8v a0h = __builtin_bit_cast(bf8v, Ah[0][l]);
            bf8v a0l = __builtin_bit_cast(bf8v, Al[0][l]);
            bf8v a1h = __builtin_bit_cast(bf8v, Ah[1][l]);
            bf8v a1l = __builtin_bit_cast(bf8v, Al[1][l]);
            acc0 = __builtin_amdgcn_mfma_f32_16x16x32_bf16(a0h, bh, acc0, 0, 0, 0);
            acc1 = __builtin_amdgcn_mfma_f32_16x16x32_bf16(a1h, bh, acc1, 0, 0, 0);
            acc0 = __builtin_amdgcn_mfma_f32_16x16x32_bf16(a0l, bh, acc0, 0, 0, 0);
            acc1 = __builtin_amdgcn_mfma_f32_16x16x32_bf16(a1l, bh, acc1, 0, 0, 0);
            acc0 = __builtin_amdgcn_mfma_f32_16x16x32_bf16(a0h, bl, acc0, 0, 0, 0);
            acc1 = __builtin_amdgcn_mfma_f32_16x16x32_bf16(a1h, bl, acc1, 0, 0, 0);
        }
    };

    auto writegb = [&](f4v a0, f4v a1) {     // ks<3 waves park partials
        float* gp = gbuf + ((ks * 4 + rs) * 2) * 272 + quad * 68 + mn * 4;
        *(f4v*)gp = a0;
        *(f4v*)(gp + 272) = a1;
    };
    auto reduceg = [&](f4v& a0, f4v& a1) {   // leader sums 3 parked + own
        const int gb = (rs * 2) * 272 + quad * 68 + mn * 4;
        a0 += *(const f4v*)(gbuf + gb);
        a0 += *(const f4v*)(gbuf + gb + 2176);
        a0 += *(const f4v*)(gbuf + gb + 4352);
        a1 += *(const f4v*)(gbuf + gb + 272);
        a1 += *(const f4v*)(gbuf + gb + 272 + 2176);
        a1 += *(const f4v*)(gbuf + gb + 272 + 4352);
    };

    // LSTM cell on an accumulator holding (i,f,g,o)
    auto lstm = [&](f4v g, float& cc) -> float {
        float i_ = fsig(g[0]), f_ = fsig(g[1]);
        float g_ = ftanh(g[2]), o_ = fsig(g[3]);
        float cn = fmaf(f_, cc, i_ * g_);
        cc = cn;
        return o_ * ftanh(cn);
    };

    // leader thread owns adjacent hid pair (hid0, hid0+1), batch mn
    const int pidx = lb * 16 + rs * 4 + quad;         // hid-pair index
    const int hid0 = lb * 32 + rs * 8 + 2 * quad;

    auto storeh = [&](unsigned* hn, unsigned* ln, float h0, float h1) {
        unsigned b0 = __float_as_uint(h0), b1 = __float_as_uint(h1);
        unsigned hiw = __builtin_amdgcn_perm(b1, b0, PERM_HI);
        float r0 = h0 - __uint_as_float(b0 & 0xffff0000u);
        float r1 = h1 - __uint_as_float(b1 & 0xffff0000u);
        unsigned low = __builtin_amdgcn_perm(__float_as_uint(r1),
                                             __float_as_uint(r0), PERM_HI);
        size_t pa = (size_t)(bgbase + mn) * 256 + pidx;
        __hip_atomic_store(hn + pa, hiw, __ATOMIC_RELAXED, __HIP_MEMORY_SCOPE_AGENT);
        __hip_atomic_store(ln + pa, low, __ATOMIC_RELAXED, __HIP_MEMORY_SCOPE_AGENT);
    };

    // h[b=w]·lin_W from hi/lo planes; result on lane 0 of the wave
    auto proj = [&]() -> float {
        const unsigned* hh = hs_hi + w * HS2 + 4 * lane;
        const unsigned* hl = hs_lo + w * HS2 + 4 * lane;
        uint4 uh = *(const uint4*)hh;
        uint4 ul = *(const uint4*)hl;
        const float4* lwp = (const float4*)(lin_W + 8 * lane);
        float4 v0 = lwp[0], v1 = lwp[1];
        #define RL(h, l) (__uint_as_float((h) << 16) + __uint_as_float((l) << 16))
        #define RH(h, l) (__uint_as_float((h) & 0xffff0000u) + __uint_as_float((l) & 0xffff0000u))
        float s = RL(uh.x, ul.x) * v0.x + RH(uh.x, ul.x) * v0.y;
        s = fmaf(RL(uh.y, ul.y), v0.z, s); s = fmaf(RH(uh.y, ul.y), v0.w, s);
        s = fmaf(RL(uh.z, ul.z), v1.x, s); s = fmaf(RH(uh.z, ul.z), v1.y, s);
        s = fmaf(RL(uh.w, ul.w), v1.z, s); s = fmaf(RH(uh.w, ul.w), v1.w, s);
        #undef RL
        #undef RH
        s += __shfl_down(s, 32); s += __shfl_down(s, 16); s += __shfl_down(s, 8);
        s += __shfl_down(s, 4);  s += __shfl_down(s, 2);  s += __shfl_down(s, 1);
        return s;
    };

    const float linb = lin_b[0];

    // encoder per-cell constants (leaders only; 16 regs)
    float encW[2][4], encB[2][4];
    if (leader) {
        #pragma unroll
        for (int p = 0; p < 2; ++p)
            #pragma unroll
            for (int g4 = 0; g4 < 4; ++g4) {
                const int j = g4 * H_ + hid0 + p;
                encW[p][g4] = enc_Wih[j];
                encB[p][g4] = enc_bih[j] + enc_bhh[j];
            }
    }

    loadA(enc_Whh);

    // h_0 = 0 (leaders cover all 512 cells per block)
    if (leader) {
        size_t pa = (size_t)(bgbase + mn) * 256 + pidx;
        __hip_atomic_store(hiA + pa, 0u, __ATOMIC_RELAXED, __HIP_MEMORY_SCOPE_AGENT);
        __hip_atomic_store(loA + pa, 0u, __ATOMIC_RELAXED, __HIP_MEMORY_SCOPE_AGENT);
    }

    float cc0 = 0.f, cc1 = 0.f;
    unsigned *hic = hiA, *loc = loA, *hin = hiB, *lon = loB;
    int ph = 0;

    // ---------------- encoder: 1024 steps ----------------
    #pragma unroll 1
    for (int t = 0; t < S_; ++t) {
        bg_barrier(arr, ph++);
        stage(hic, loc);
        float xv = leader ? inputs[(size_t)(bgbase + mn) * S_ + t] : 0.f;
        __syncthreads();
        f4v acc0, acc1;
        dots(acc0, acc1);
        if (!leader) writegb(acc0, acc1);
        __syncthreads();
        if (leader) {
            reduceg(acc0, acc1);
            #pragma unroll
            for (int g4 = 0; g4 < 4; ++g4) {
                acc0[g4] += fmaf(xv, encW[0][g4], encB[0][g4]);
                acc1[g4] += fmaf(xv, encW[1][g4], encB[1][g4]);
            }
            float h0 = lstm(acc0, cc0);
            float h1 = lstm(acc1, cc1);
            storeh(hin, lon, h0, h1);
        }
        unsigned* t1 = hic; hic = hin; hin = t1;
        unsigned* t2 = loc; loc = lon; lon = t2;
    }

    // ---------------- xcor phase + decoder weight swap ----------------
    bg_barrier(arr, ph++);
    if (lb == 0) {          // xcor[b] = x0_true - (h_enc·lin_W + lin_b)
        stage(hic, loc);
        __syncthreads();
        float s = proj();
        if (lane == 0) {
            float x0 = inputs[(size_t)(bgbase + w) * S_ + (S_ - 1)];
            __hip_atomic_store(&xcor[bgbase + w],
                               __float_as_uint(0) * 0.f + (x0 - (s + linb)),
                               __ATOMIC_RELAXED, __HIP_MEMORY_SCOPE_AGENT);
        }
    }
    loadA(W2);

    // hoisted loop-invariant decoder biases (leaders only; validated in the
    // two passing runs R6/R7 of this session)
    f4v db0{0.f,0.f,0.f,0.f}, db1{0.f,0.f,0.f,0.f};
    if (leader) {
        #pragma unroll
        for (int g4 = 0; g4 < 4; ++g4) {
            float2 d = *(const float2*)(dbias + g4 * H_ + hid0);
            db0[g4] = d.x; db1[g4] = d.y;
        }
    }

    // ---------------- decoder: 256 steps ----------------
    #pragma unroll 1
    for (int t = 0; t < T_; ++t) {
        bg_barrier(arr, ph++);
        stage(hic, loc);
        __syncthreads();
        f4v acc0, acc1;
        dots(acc0, acc1);
        if (!leader) writegb(acc0, acc1);
        __syncthreads();
        if (lb == 0 && t > 0) {        // out[:, t-1] = h_t·lin_W + lin_b
            float s = proj();
            if (lane == 0)
                out[(size_t)(bgbase + w) * T_ + (t - 1)] = s + linb;
        }
        if (leader) {
            reduceg(acc0, acc1);
            acc0 += db0;
            acc1 += db1;
            if (t == 0) {   // true x0 correction through dec_Wih
                float xc = __hip_atomic_load(&xcor[bgbase + mn],
                                             __ATOMIC_RELAXED, __HIP_MEMORY_SCOPE_AGENT);
                #pragma unroll
                for (int g4 = 0; g4 < 4; ++g4) {
                    float2 dw = *(const float2*)(dec_Wih + g4 * H_ + hid0);
                    acc0[g4] = fmaf(xc, dw.x, acc0[g4]);
                    acc1[g4] = fmaf(xc, dw.y, acc1[g4]);
                }
            }
            float h0 = lstm(acc0, cc0);
            float h1 = lstm(acc1, cc1);
            storeh(hin, lon, h0, h1);
        }
        unsigned* t1 = hic; hic = hin; hin = t1;
        unsigned* t2 = loc; loc = lon; lon = t2;
    }

    // ---------------- epilogue: out[:, T-1] ----------------
    bg_barrier(arr, ph++);
    if (lb == 0) {
        stage(hic, loc);
        __syncthreads();
        float s = proj();
        if (lane == 0)
            out[(size_t)(bgbase + w) * T_ + (T_ - 1)] = s + linb;
    }
}

// ---------------------------------------------------------------------------
extern "C" void kernel_launch(void* const* d_in, const int* in_sizes, int n_in,
                              void* d_out, int out_size, void* d_ws, size_t ws_size,
                              hipStream_t stream)
{
    (void)in_sizes; (void)n_in; (void)out_size; (void)ws_size;

    const float* inputs  = (const float*)d_in[0];
    const float* enc_Wih = (const float*)d_in[1];
    const float* enc_Whh = (const float*)d_in[2];
    const float* enc_bih = (const float*)d_in[3];
    const float* enc_bhh = (const float*)d_in[4];
    const float* dec_Wih = (const float*)d_in[5];
    const float* dec_Whh = (const float*)d_in[6];
    const float* dec_bih = (const float*)d_in[7];
    const float* dec_bhh = (const float*)d_in[8];
    const float* lin_W   = (const float*)d_in[9];
    const float* lin_b   = (const float*)d_in[10];
    float* out = (float*)d_out;

    // ws: W2 (4MB) | dbias (8KB) | hiA|loA|hiB|loB (1MB) | xcor | bars
    float* W2      = (float*)d_ws;
    float* dbias   = W2 + (size_t)G4_ * H_;
    unsigned* hiA  = (unsigned*)(dbias + G4_);
    unsigned* loA  = hiA + (size_t)B_ * 256;
    unsigned* hiB  = loA + (size_t)B_ * 256;
    unsigned* loB  = hiB + (size_t)B_ * 256;
    float* xcor    = (float*)(loB + (size_t)B_ * 256);
    unsigned* bars = (unsigned*)(xcor + B_);

    hipMemsetAsync((void*)bars, 0, NBG * 64 * sizeof(unsigned), stream);

    hipLaunchKernelGGL(fuse_dec_weights, dim3((G4_ * H_) / 256), dim3(256), 0, stream,
                       dec_Whh, dec_Wih, lin_W, dec_bih, dec_bhh, lin_b, W2, dbias);

    void* args[] = {
        (void*)&inputs, (void*)&enc_Wih, (void*)&enc_bih, (void*)&enc_bhh,
        (void*)&dec_Wih, (void*)&lin_W, (void*)&lin_b,
        (void*)&enc_Whh, (void*)&W2, (void*)&dbias,
        (void*)&hiA, (void*)&loA, (void*)&hiB, (void*)&loB,
        (void*)&xcor, (void*)&bars, (void*)&out
    };
    hipLaunchCooperativeKernel((void*)seq2seq_kernel, dim3(NBLK), dim3(NTHR),
                               args, 0, stream);
}